// Round 11
// baseline (233.614 us; speedup 1.0000x reference)
//
#include <hip/hip_runtime.h>
#include <math.h>

#define NCLI 100
#define CPAD 112                  // clients padded to 7*16
#define DK   32                   // d-rows per chunk
#define RAWB 16384                // raw fp32 buffer bytes (1024 float4 slots, 800 used)
#define BFB  (CPAD * DK * 2)      // 7168 B bf16 transposed buffer
#define GBLK 1024                 // 4 blocks/CU x 256 CU

typedef short bf16x8 __attribute__((ext_vector_type(8)));  // 8 bf16 (4 VGPRs)
typedef float f32x4  __attribute__((ext_vector_type(4)));

// bf16 buffer byte offset for (client c, k-offset t). Row stride 64B = 4 x 16B
// slots; slot = ((c>>1)^(c>>3)) & 3.
// Fragment reads (c = 16T + l, l=0..15, 4 kgrps): per (bank-half = c&1,
// slot-group) exactly 8 lanes -> 8 accesses/bank = the b128 minimum (optimal).
// Staging writes (c = 4cg+j): slot varies with cg -> spread, ~free.
__device__ __forceinline__ int bf_byte(int c, int t) {
    int s = ((c >> 1) ^ (c >> 3)) & 3;
    return c * 64 + ((t * 2) ^ (s << 4));
}

// fp32 -> bf16 (RNE), bit pattern as ushort
__device__ __forceinline__ unsigned short f2bf(float x) {
    unsigned u = __float_as_uint(x);
    unsigned r = (u + 0x7fffu + ((u >> 16) & 1u)) >> 16;
    return (unsigned short)r;
}

// ---------------- tiny zero kernel (graph-safe G clear) ----------------
__global__ void zero_kernel(float4* __restrict__ p, int n4) {
    int i = blockIdx.x * blockDim.x + threadIdx.x;
    if (i < n4) p[i] = make_float4(0.f, 0.f, 0.f, 0.f);
}

// ---- async DMA: chunk (32 rows x 400B, CONTIGUOUS in A) -> linear LDS raw ----
// 4 uniform global_load_lds(16B) per thread; per-lane global addr clamped so all
// waves issue exactly 4 (uniform vmcnt); LDS dest = wave-uniform base + lane*16.
// Zero register data path -> nothing to spill, nothing alive across barriers.
__device__ __forceinline__ void stage_issue(const float* __restrict__ A, long c0,
                                            char* raw, int tid, long dtot) {
    const long gword0 = c0 * (DK * NCLI);
    const long gmax = dtot * NCLI - 4;       // last safe float4 word start
    const int wbyte = (tid & ~63) << 4;      // wave-uniform byte base
#pragma unroll
    for (int i = 0; i < 4; ++i) {
        int f = i * 256 + tid;
        if (f > 799) f = 799;                // pad issues re-load last float4
        long gw = gword0 + (long)f * 4;
        if (gw > gmax) gw = gmax;
        __builtin_amdgcn_global_load_lds(
            (const __attribute__((address_space(1))) unsigned*)(A + gw),
            (__attribute__((address_space(3))) unsigned*)(raw + i * 4096 + wbyte),
            16, 0, 0);
    }
}

// ---- LDS->LDS transpose + fp32->bf16 convert (raw linear -> bf swizzled) ----
// 200 units (4-row x 4-col each), one per thread for tid<200.
__device__ __forceinline__ void transpose_convert(const char* raw, char* bf,
                                                  int tid, long d0, long dtot) {
    if (tid < (DK / 4) * 25) {
        const int rg = tid / 25;             // 4-row group 0..7
        const int cg = tid - rg * 25;        // 4-col group 0..24
        float4 v[4];
#pragma unroll
        for (int r = 0; r < 4; ++r) {
            v[r] = *(const float4*)(raw + (((rg * 4 + r) * 25 + cg) << 4));
            if (d0 + rg * 4 + r >= dtot) v[r] = make_float4(0.f, 0.f, 0.f, 0.f);
        }
#pragma unroll
        for (int j = 0; j < 4; ++j) {
            const int c = cg * 4 + j;
            ushort4 p;
            p.x = f2bf(((const float*)&v[0])[j]);
            p.y = f2bf(((const float*)&v[1])[j]);
            p.z = f2bf(((const float*)&v[2])[j]);
            p.w = f2bf(((const float*)&v[3])[j]);
            *(ushort4*)(bf + bf_byte(c, rg * 4)) = p;   // 8B, 8B-aligned
        }
    }
}

// Wave W owns 16x16 output tiles: row a=W, b=W..6 (7-W tiles) and, for W>0,
// row a=7-W, b=7-W..6 (W tiles). Exactly 7 tiles per wave, A-frags {W, 7-W}.
template <int W>
__device__ __forceinline__ void compute_chunk(const char* bf, f32x4 acc[7]) {
    const int lane = threadIdx.x & 63;
    const int lrow = lane & 15;        // row/col within tile
    const int kgrp = lane >> 4;        // k-group 0..3 (8 bf16 each)
    constexpr int NB = 7 - W;          // b = W..6
#pragma unroll
    for (int kk = 0; kk < DK; kk += 32) {
        const int kb = kk + kgrp * 8;
        bf16x8 bfr[NB];
#pragma unroll
        for (int j = 0; j < NB; ++j)
            bfr[j] = *(const bf16x8*)(bf + bf_byte((W + j) * 16 + lrow, kb));
        bf16x8 a0 = *(const bf16x8*)(bf + bf_byte(W * 16 + lrow, kb));
#pragma unroll
        for (int j = 0; j < NB; ++j)
            acc[j] = __builtin_amdgcn_mfma_f32_16x16x32_bf16(a0, bfr[j], acc[j], 0, 0, 0);
        if constexpr (W > 0) {
            bf16x8 a1 = *(const bf16x8*)(bf + bf_byte((7 - W) * 16 + lrow, kb));
#pragma unroll
            for (int j = 0; j < W; ++j)
                acc[NB + j] = __builtin_amdgcn_mfma_f32_16x16x32_bf16(
                    a1, bfr[NB - W + j], acc[NB + j], 0, 0, 0);
        }
    }
}

template <int W>
__device__ __forceinline__ void store_acc(float* __restrict__ G, const f32x4 acc[7]) {
    const int lane = threadIdx.x & 63;
    const int cn = lane & 15;                 // output col within tile
    const int r0 = (lane >> 4) * 4;           // output row base within tile
#pragma unroll
    for (int j = 0; j < 7 - W; ++j) {         // tiles (W, W+j)
#pragma unroll
        for (int r = 0; r < 4; ++r) {
            int i = W * 16 + r0 + r;
            int k = (W + j) * 16 + cn;
            if (i < NCLI && k < NCLI) atomicAdd(&G[i * NCLI + k], acc[j][r]);
        }
    }
    if constexpr (W > 0) {
#pragma unroll
        for (int j = 0; j < W; ++j) {         // tiles (7-W, 7-W+j)
#pragma unroll
            for (int r = 0; r < 4; ++r) {
                int i = (7 - W) * 16 + r0 + r;
                int k = (7 - W + j) * 16 + cn;
                if (i < NCLI && k < NCLI) atomicAdd(&G[i * NCLI + k], acc[7 - W + j][r]);
            }
        }
    }
}

// ---------------- MFMA Gram, async-DMA pipelined, 4 blocks/CU ----------------
// r9 structure (zero-register DMA double-buffer, counted vmcnt, raw barriers)
// at DK=32 so LDS = 2x16K + 7K -> 4 blocks/CU: 16 waves in 4 INDEPENDENT phase
// groups (r9 had 2 lockstep groups -> phase-aligned stalls left HBM idle).
__global__ __launch_bounds__(256, 4) void gram_mfma(const float* __restrict__ A,
                                                    float* __restrict__ G,
                                                    long dtot, int nchunks) {
    __shared__ char lds[2 * RAWB + BFB];   // 39936 B -> 4 blocks/CU
    char* bf = lds + 2 * RAWB;
    const int tid = threadIdx.x;
    const int wid = tid >> 6;

    // zero bf pad-client rows 100..111 once (whole rows zero, swizzle-internal)
    for (int u = tid; u < (CPAD - NCLI) * 16; u += 256)
        ((unsigned*)(bf + NCLI * 64))[u] = 0u;
    __syncthreads();

    f32x4 acc[7];
#pragma unroll
    for (int q = 0; q < 7; ++q) acc[q] = (f32x4)(0.0f);

    int nb = 0;
    if ((int)blockIdx.x < nchunks)
        nb = (nchunks - 1 - (int)blockIdx.x) / (int)gridDim.x + 1;

    if (nb > 0)
        stage_issue(A, (long)blockIdx.x, lds, tid, dtot);   // prologue -> raw0

    for (int e = 0; e < nb; ++e) {
        char* raw_cur = lds + (e & 1) * RAWB;
        if (e + 1 < nb) {
            stage_issue(A, (long)blockIdx.x + (long)(e + 1) * gridDim.x,
                        lds + ((e + 1) & 1) * RAWB, tid, dtot);
            asm volatile("s_waitcnt vmcnt(4)" ::: "memory");   // drain chunk e only
        } else {
            asm volatile("s_waitcnt vmcnt(0)" ::: "memory");
        }
        __builtin_amdgcn_s_barrier();
        asm volatile("" ::: "memory");

        transpose_convert(raw_cur, bf, tid,
                          ((long)blockIdx.x + (long)e * gridDim.x) * DK, dtot);

        asm volatile("s_waitcnt lgkmcnt(0)" ::: "memory");
        __builtin_amdgcn_s_barrier();
        asm volatile("" ::: "memory");

        if (wid == 0)      compute_chunk<0>(bf, acc);
        else if (wid == 1) compute_chunk<1>(bf, acc);
        else if (wid == 2) compute_chunk<2>(bf, acc);
        else               compute_chunk<3>(bf, acc);
    }

    if (wid == 0)      store_acc<0>(G, acc);
    else if (wid == 1) store_acc<1>(G, acc);
    else if (wid == 2) store_acc<2>(G, acc);
    else               store_acc<3>(G, acc);
}

// ---------------- Weights kernel: full FoolsGold weight computation, single block ----------------
__global__ __launch_bounds__(128) void weights_kernel(const float* __restrict__ G,
                                                      float* __restrict__ w) {
    __shared__ float cs[NCLI][NCLI + 1];
    __shared__ float nrm[NCLI], maxcs[NCLI], wv[NCLI];
    __shared__ float red[2];
    const int t = threadIdx.x;

    if (t < NCLI) {
        float g = G[t * NCLI + t];
        nrm[t] = fmaxf(sqrtf(g), 1e-12f);
    }
    __syncthreads();

    for (int idx = t; idx < NCLI * NCLI; idx += 128) {
        int i = idx / NCLI;
        int j = idx - i * NCLI;
        int a = i < j ? i : j;
        int b = i < j ? j : i;
        float c = G[a * NCLI + b] / (nrm[i] * nrm[j]);
        if (i == j) c -= 1.0f;
        cs[i][j] = c;
    }
    __syncthreads();

    if (t < NCLI) {
        float m = -1e30f;
        for (int j = 0; j < NCLI; ++j) m = fmaxf(m, cs[t][j]);
        maxcs[t] = m;
    }
    __syncthreads();

    if (t < NCLI) {
        float mi = maxcs[t];
        float m = -1e30f;
        for (int j = 0; j < NCLI; ++j) {
            float v = cs[t][j];
            float mj = maxcs[j];
            if (t != j && mi < mj) v *= mi / mj;  // pardoning
            m = fmaxf(m, v);
        }
        float x = 1.0f - m;
        x = fminf(fmaxf(x, 0.0f), 1.0f);
        wv[t] = x;
    }
    __syncthreads();

    if (t == 0) {
        float m = 0.0f;
        for (int i = 0; i < NCLI; ++i) m = fmaxf(m, wv[i]);
        red[0] = m;
    }
    __syncthreads();

    if (t < NCLI) {
        float x = wv[t] / red[0];
        if (x == 1.0f) x = 0.99f;
        float l = logf(x / (1.0f - x)) + 0.5f;
        float flag = isinf(l) ? 1.0f : 0.0f;   // torch: wv[isinf(wv)+wv > 1] = 1
        l = (flag + l > 1.0f) ? 1.0f : l;
        l = (l < 0.0f) ? 0.0f : l;
        wv[t] = l;
    }
    __syncthreads();

    if (t == 0) {
        float s = 0.0f;
        for (int i = 0; i < NCLI; ++i) s += wv[i];
        red[1] = s;
    }
    __syncthreads();

    if (t < NCLI) w[t] = wv[t] / red[1];
}

// ---------------- Output kernel: out[j] = dot(A[j][:], w), quarter-row ----------------
// 4 lanes per row (q = (lane&3) + 4k): wave touches 16 rows x 64B contiguous
// segments per instruction -> small L1 window, no thrash (r10: -40us).
// Tail-first block->row mapping preserves gram's L3 tail residency.
__global__ __launch_bounds__(256) void out_kernel(const float* __restrict__ A,
                                                  const float* __restrict__ w,
                                                  float* __restrict__ out, int d,
                                                  int nblocks) {
    __shared__ float4 w4s[NCLI / 4];
    if (threadIdx.x < NCLI / 4) w4s[threadIdx.x] = ((const float4*)w)[threadIdx.x];
    __syncthreads();

    const int lane = threadIdx.x & 63;
    const int wid = threadIdx.x >> 6;
    const int q0 = lane & 3;                  // quarter id 0..3
    const int rsub = lane >> 2;               // row-within-wave 0..15

    const long rb = (long)(nblocks - 1 - blockIdx.x) * 64;   // 64 rows/block, tail-first
    const long row = rb + wid * 16 + rsub;
    if (row >= d) return;

    const float4* r4 = (const float4*)(A + row * NCLI);
    float s = 0.0f;
#pragma unroll
    for (int k = 0; k < 6; ++k) {             // q = q0 + 4k  (0..23)
        float4 v = r4[q0 + 4 * k];
        float4 ww = w4s[q0 + 4 * k];
        s += v.x * ww.x + v.y * ww.y + v.z * ww.z + v.w * ww.w;
    }
    if (q0 == 0) {                            // tail q = 24
        float4 v = r4[24];
        float4 ww = w4s[24];
        s += v.x * ww.x + v.y * ww.y + v.z * ww.z + v.w * ww.w;
    }
    // reduce across the 4-lane quarter group
    s += __shfl_xor(s, 1, 64);
    s += __shfl_xor(s, 2, 64);
    if (q0 == 0) out[row] = s;
}

extern "C" void kernel_launch(void* const* d_in, const int* in_sizes, int n_in,
                              void* d_out, int out_size, void* d_ws, size_t ws_size,
                              hipStream_t stream) {
    const float* A = (const float*)d_in[0];
    float* out = (float*)d_out;
    const int d = in_sizes[0] / NCLI;

    float* G = (float*)d_ws;           // 100*100 f32 (upper triangle used)
    float* w = G + NCLI * NCLI;        // 100 f32 weights

    const int n4 = (NCLI * NCLI) / 4;  // 2500 float4
    zero_kernel<<<(n4 + 255) / 256, 256, 0, stream>>>((float4*)G, n4);

    const int nchunks = (d + DK - 1) / DK;
    const int gblocks = nchunks < GBLK ? nchunks : GBLK;
    gram_mfma<<<gblocks, 256, 0, stream>>>(A, G, (long)d, nchunks);

    weights_kernel<<<1, 128, 0, stream>>>(G, w);

    const int oblocks = (d + 63) / 64;  // 64 rows per block
    out_kernel<<<oblocks, 256, 0, stream>>>(A, w, out, d, oblocks);
}

// Round 12
// 224.841 us; speedup vs baseline: 1.0390x; 1.0390x over previous
//
#include <hip/hip_runtime.h>
#include <math.h>

#define NCLI 100
#define CPAD 112                  // clients padded to 7*16
#define DK   32                   // d-rows per chunk
#define RAWB 16384                // raw fp32 buffer bytes (800 float4 used + pad)
#define BFB  (CPAD * DK * 2)      // 7168 B bf16 transposed buffer
#define GBLK 512                  // 2 blocks/CU x 256 CU

typedef short bf16x8 __attribute__((ext_vector_type(8)));  // 8 bf16 (4 VGPRs)
typedef float f32x4  __attribute__((ext_vector_type(4)));

// bf16 buffer byte offset for (client c, k-offset t). Row stride 64B = 4 x 16B
// slots; slot = ((c>>1)^(c>>3)) & 3. Fragment reads: 8 accesses/bank = b128
// minimum (optimal). Staging writes spread via cg bits (verified r11, absmax ok).
__device__ __forceinline__ int bf_byte(int c, int t) {
    int s = ((c >> 1) ^ (c >> 3)) & 3;
    return c * 64 + ((t * 2) ^ (s << 4));
}

// fp32 -> bf16 (RNE), bit pattern as ushort
__device__ __forceinline__ unsigned short f2bf(float x) {
    unsigned u = __float_as_uint(x);
    unsigned r = (u + 0x7fffu + ((u >> 16) & 1u)) >> 16;
    return (unsigned short)r;
}

// ---------------- tiny zero kernel (graph-safe G clear) ----------------
__global__ void zero_kernel(float4* __restrict__ p, int n4) {
    int i = blockIdx.x * blockDim.x + threadIdx.x;
    if (i < n4) p[i] = make_float4(0.f, 0.f, 0.f, 0.f);
}

// ---- async DMA: chunk (32 rows x 400B, CONTIGUOUS in A) -> linear LDS raw ----
// 4 uniform global_load_lds(16B) per thread (clamped -> vmcnt uniform).
// Zero register data path -> nothing to spill, nothing alive across barriers.
__device__ __forceinline__ void stage_issue(const float* __restrict__ A, long c0,
                                            char* raw, int tid, long dtot) {
    const long gword0 = c0 * (DK * NCLI);
    const long gmax = dtot * NCLI - 4;       // last safe float4 word start
    const int wbyte = (tid & ~63) << 4;      // wave-uniform byte base
#pragma unroll
    for (int i = 0; i < 4; ++i) {
        int f = i * 256 + tid;
        if (f > 799) f = 799;                // pad issues re-load last float4
        long gw = gword0 + (long)f * 4;
        if (gw > gmax) gw = gmax;
        __builtin_amdgcn_global_load_lds(
            (const __attribute__((address_space(1))) unsigned*)(A + gw),
            (__attribute__((address_space(3))) unsigned*)(raw + i * 4096 + wbyte),
            16, 0, 0);
    }
}

// ---- LDS->LDS transpose + fp32->bf16 convert (raw linear -> bf swizzled) ----
// 200 units (4-row x 4-col each), one per thread for tid<200.
__device__ __forceinline__ void transpose_convert(const char* raw, char* bf,
                                                  int tid, long d0, long dtot) {
    if (tid < (DK / 4) * 25) {
        const int rg = tid / 25;             // 4-row group 0..7
        const int cg = tid - rg * 25;        // 4-col group 0..24
        float4 v[4];
#pragma unroll
        for (int r = 0; r < 4; ++r) {
            v[r] = *(const float4*)(raw + (((rg * 4 + r) * 25 + cg) << 4));
            if (d0 + rg * 4 + r >= dtot) v[r] = make_float4(0.f, 0.f, 0.f, 0.f);
        }
#pragma unroll
        for (int j = 0; j < 4; ++j) {
            const int c = cg * 4 + j;
            ushort4 p;
            p.x = f2bf(((const float*)&v[0])[j]);
            p.y = f2bf(((const float*)&v[1])[j]);
            p.z = f2bf(((const float*)&v[2])[j]);
            p.w = f2bf(((const float*)&v[3])[j]);
            *(ushort4*)(bf + bf_byte(c, rg * 4)) = p;   // 8B, 8B-aligned
        }
    }
}

// Wave W owns 16x16 output tiles: row a=W, b=W..6 (7-W tiles) and, for W>0,
// row a=7-W, b=7-W..6 (W tiles). Exactly 7 tiles per wave, A-frags {W, 7-W}.
template <int W>
__device__ __forceinline__ void compute_chunk(const char* bf, f32x4 acc[7]) {
    const int lane = threadIdx.x & 63;
    const int lrow = lane & 15;        // row/col within tile
    const int kgrp = lane >> 4;        // k-group 0..3 (8 bf16 each)
    constexpr int NB = 7 - W;          // b = W..6
#pragma unroll
    for (int kk = 0; kk < DK; kk += 32) {
        const int kb = kk + kgrp * 8;
        bf16x8 bfr[NB];
#pragma unroll
        for (int j = 0; j < NB; ++j)
            bfr[j] = *(const bf16x8*)(bf + bf_byte((W + j) * 16 + lrow, kb));
        bf16x8 a0 = *(const bf16x8*)(bf + bf_byte(W * 16 + lrow, kb));
#pragma unroll
        for (int j = 0; j < NB; ++j)
            acc[j] = __builtin_amdgcn_mfma_f32_16x16x32_bf16(a0, bfr[j], acc[j], 0, 0, 0);
        if constexpr (W > 0) {
            bf16x8 a1 = *(const bf16x8*)(bf + bf_byte((7 - W) * 16 + lrow, kb));
#pragma unroll
            for (int j = 0; j < W; ++j)
                acc[NB + j] = __builtin_amdgcn_mfma_f32_16x16x32_bf16(
                    a1, bfr[NB - W + j], acc[NB + j], 0, 0, 0);
        }
    }
}

template <int W>
__device__ __forceinline__ void store_acc(float* __restrict__ G, const f32x4 acc[7]) {
    const int lane = threadIdx.x & 63;
    const int cn = lane & 15;                 // output col within tile
    const int r0 = (lane >> 4) * 4;           // output row base within tile
#pragma unroll
    for (int j = 0; j < 7 - W; ++j) {         // tiles (W, W+j)
#pragma unroll
        for (int r = 0; r < 4; ++r) {
            int i = W * 16 + r0 + r;
            int k = (W + j) * 16 + cn;
            if (i < NCLI && k < NCLI) atomicAdd(&G[i * NCLI + k], acc[j][r]);
        }
    }
    if constexpr (W > 0) {
#pragma unroll
        for (int j = 0; j < W; ++j) {         // tiles (7-W, 7-W+j)
#pragma unroll
            for (int r = 0; r < 4; ++r) {
                int i = (7 - W) * 16 + r0 + r;
                int k = (7 - W + j) * 16 + cn;
                if (i < NCLI && k < NCLI) atomicAdd(&G[i * NCLI + k], acc[7 - W + j][r]);
            }
        }
    }
}

// ---------------- MFMA Gram, async-DMA pipelined, PREFETCH DEPTH 2 ----------------
// r11 evidence: per-chunk size-independent cost ~2600cyc => depth-1's vmcnt wait
// exposes HBM latency every chunk. Depth-2: 3 rotating raw buffers; chunk e's
// wait happens ~2 iterations (~5000cyc) after issue -> latency fully hidden.
// Wait counts: steady = vmcnt(8) (chunks e+1,e+2 in flight, 4 issues each);
// tail = vmcnt(4), vmcnt(0). Buffer safety: write raw[(e+2)%3] == raw[(e-1)%3],
// whose last reads (transpose e-1) drained at that iter's lgkmcnt(0)+barrier.
__global__ __launch_bounds__(256, 2) void gram_mfma(const float* __restrict__ A,
                                                    float* __restrict__ G,
                                                    long dtot, int nchunks) {
    __shared__ char lds[3 * RAWB + BFB];   // 56320 B -> 2 blocks/CU
    char* bf = lds + 3 * RAWB;
    const int tid = threadIdx.x;
    const int wid = tid >> 6;

    // zero bf pad-client rows 100..111 once (whole rows zero, swizzle-internal)
    for (int u = tid; u < (CPAD - NCLI) * 16; u += 256)
        ((unsigned*)(bf + NCLI * 64))[u] = 0u;
    __syncthreads();

    f32x4 acc[7];
#pragma unroll
    for (int q = 0; q < 7; ++q) acc[q] = (f32x4)(0.0f);

    int nb = 0;
    if ((int)blockIdx.x < nchunks)
        nb = (nchunks - 1 - (int)blockIdx.x) / (int)gridDim.x + 1;

    // prologue: prefetch chunks 0 and 1
    if (nb > 0) stage_issue(A, (long)blockIdx.x, lds, tid, dtot);
    if (nb > 1) stage_issue(A, (long)blockIdx.x + gridDim.x, lds + RAWB, tid, dtot);

    for (int e = 0; e < nb; ++e) {
        char* raw_cur = lds + (e % 3) * RAWB;
        if (e + 2 < nb) {
            stage_issue(A, (long)blockIdx.x + (long)(e + 2) * gridDim.x,
                        lds + ((e + 2) % 3) * RAWB, tid, dtot);
            asm volatile("s_waitcnt vmcnt(8)" ::: "memory");   // drain chunk e only
        } else if (e + 1 < nb) {
            asm volatile("s_waitcnt vmcnt(4)" ::: "memory");
        } else {
            asm volatile("s_waitcnt vmcnt(0)" ::: "memory");
        }
        __builtin_amdgcn_s_barrier();
        asm volatile("" ::: "memory");

        transpose_convert(raw_cur, bf, tid,
                          ((long)blockIdx.x + (long)e * gridDim.x) * DK, dtot);

        asm volatile("s_waitcnt lgkmcnt(0)" ::: "memory");
        __builtin_amdgcn_s_barrier();
        asm volatile("" ::: "memory");

        if (wid == 0)      compute_chunk<0>(bf, acc);
        else if (wid == 1) compute_chunk<1>(bf, acc);
        else if (wid == 2) compute_chunk<2>(bf, acc);
        else               compute_chunk<3>(bf, acc);
    }

    if (wid == 0)      store_acc<0>(G, acc);
    else if (wid == 1) store_acc<1>(G, acc);
    else if (wid == 2) store_acc<2>(G, acc);
    else               store_acc<3>(G, acc);
}

// ---------------- Weights kernel: full FoolsGold weight computation, single block ----------------
__global__ __launch_bounds__(128) void weights_kernel(const float* __restrict__ G,
                                                      float* __restrict__ w) {
    __shared__ float cs[NCLI][NCLI + 1];
    __shared__ float nrm[NCLI], maxcs[NCLI], wv[NCLI];
    __shared__ float red[2];
    const int t = threadIdx.x;

    if (t < NCLI) {
        float g = G[t * NCLI + t];
        nrm[t] = fmaxf(sqrtf(g), 1e-12f);
    }
    __syncthreads();

    for (int idx = t; idx < NCLI * NCLI; idx += 128) {
        int i = idx / NCLI;
        int j = idx - i * NCLI;
        int a = i < j ? i : j;
        int b = i < j ? j : i;
        float c = G[a * NCLI + b] / (nrm[i] * nrm[j]);
        if (i == j) c -= 1.0f;
        cs[i][j] = c;
    }
    __syncthreads();

    if (t < NCLI) {
        float m = -1e30f;
        for (int j = 0; j < NCLI; ++j) m = fmaxf(m, cs[t][j]);
        maxcs[t] = m;
    }
    __syncthreads();

    if (t < NCLI) {
        float mi = maxcs[t];
        float m = -1e30f;
        for (int j = 0; j < NCLI; ++j) {
            float v = cs[t][j];
            float mj = maxcs[j];
            if (t != j && mi < mj) v *= mi / mj;  // pardoning
            m = fmaxf(m, v);
        }
        float x = 1.0f - m;
        x = fminf(fmaxf(x, 0.0f), 1.0f);
        wv[t] = x;
    }
    __syncthreads();

    if (t == 0) {
        float m = 0.0f;
        for (int i = 0; i < NCLI; ++i) m = fmaxf(m, wv[i]);
        red[0] = m;
    }
    __syncthreads();

    if (t < NCLI) {
        float x = wv[t] / red[0];
        if (x == 1.0f) x = 0.99f;
        float l = logf(x / (1.0f - x)) + 0.5f;
        float flag = isinf(l) ? 1.0f : 0.0f;   // torch: wv[isinf(wv)+wv > 1] = 1
        l = (flag + l > 1.0f) ? 1.0f : l;
        l = (l < 0.0f) ? 0.0f : l;
        wv[t] = l;
    }
    __syncthreads();

    if (t == 0) {
        float s = 0.0f;
        for (int i = 0; i < NCLI; ++i) s += wv[i];
        red[1] = s;
    }
    __syncthreads();

    if (t < NCLI) w[t] = wv[t] / red[1];
}

// ---------------- Output kernel: out[j] = dot(A[j][:], w), quarter-row ----------------
// 4 lanes per row (q = (lane&3) + 4k): wave touches 16 rows x 64B contiguous
// segments per instruction -> small L1 window, no thrash (r10: -40us).
// Tail-first block->row mapping preserves gram's L3 tail residency.
__global__ __launch_bounds__(256) void out_kernel(const float* __restrict__ A,
                                                  const float* __restrict__ w,
                                                  float* __restrict__ out, int d,
                                                  int nblocks) {
    __shared__ float4 w4s[NCLI / 4];
    if (threadIdx.x < NCLI / 4) w4s[threadIdx.x] = ((const float4*)w)[threadIdx.x];
    __syncthreads();

    const int lane = threadIdx.x & 63;
    const int wid = threadIdx.x >> 6;
    const int q0 = lane & 3;                  // quarter id 0..3
    const int rsub = lane >> 2;               // row-within-wave 0..15

    const long rb = (long)(nblocks - 1 - blockIdx.x) * 64;   // 64 rows/block, tail-first
    const long row = rb + wid * 16 + rsub;
    if (row >= d) return;

    const float4* r4 = (const float4*)(A + row * NCLI);
    float s = 0.0f;
#pragma unroll
    for (int k = 0; k < 6; ++k) {             // q = q0 + 4k  (0..23)
        float4 v = r4[q0 + 4 * k];
        float4 ww = w4s[q0 + 4 * k];
        s += v.x * ww.x + v.y * ww.y + v.z * ww.z + v.w * ww.w;
    }
    if (q0 == 0) {                            // tail q = 24
        float4 v = r4[24];
        float4 ww = w4s[24];
        s += v.x * ww.x + v.y * ww.y + v.z * ww.z + v.w * ww.w;
    }
    // reduce across the 4-lane quarter group
    s += __shfl_xor(s, 1, 64);
    s += __shfl_xor(s, 2, 64);
    if (q0 == 0) out[row] = s;
}

extern "C" void kernel_launch(void* const* d_in, const int* in_sizes, int n_in,
                              void* d_out, int out_size, void* d_ws, size_t ws_size,
                              hipStream_t stream) {
    const float* A = (const float*)d_in[0];
    float* out = (float*)d_out;
    const int d = in_sizes[0] / NCLI;

    float* G = (float*)d_ws;           // 100*100 f32 (upper triangle used)
    float* w = G + NCLI * NCLI;        // 100 f32 weights

    const int n4 = (NCLI * NCLI) / 4;  // 2500 float4
    zero_kernel<<<(n4 + 255) / 256, 256, 0, stream>>>((float4*)G, n4);

    const int nchunks = (d + DK - 1) / DK;
    const int gblocks = nchunks < GBLK ? nchunks : GBLK;
    gram_mfma<<<gblocks, 256, 0, stream>>>(A, G, (long)d, nchunks);

    weights_kernel<<<1, 128, 0, stream>>>(G, w);

    const int oblocks = (d + 63) / 64;  // 64 rows per block
    out_kernel<<<oblocks, 256, 0, stream>>>(A, w, out, d, oblocks);
}

// Round 13
// 207.277 us; speedup vs baseline: 1.1271x; 1.0847x over previous
//
#include <hip/hip_runtime.h>
#include <math.h>

#define NCLI 100
#define CPAD 112                  // clients padded to 7*16
#define DK   128                  // d-rows per chunk
#define RAWB 53248                // raw fp32 buffer bytes (13 x 4096; 3200 float4 used)
#define BFB  (CPAD * 256)         // 28672 B bf16 transposed buffer (256B row stride)
#define GBLK 256                  // 1 block/CU x 256 CU (132KB LDS)

typedef short bf16x8 __attribute__((ext_vector_type(8)));  // 8 bf16 (4 VGPRs)
typedef float f32x4  __attribute__((ext_vector_type(4)));

// bf16 buffer byte offset for (client c, k-offset t). Row stride 256B = 16 x 16B
// slots; slot = bitpairswap(c&15) ^ (c>>4)  (r6-verified).
// Fragment reads: bank = off bits[6:2] only (c*256 = bank-0 aligned);
// (kgrp ^ s) spans 16 slots -> 8 lanes/bank-group -> 8 accesses/bank = the b128
// minimum (optimal). Transpose writes spread via cg bits (~8 slots).
__device__ __forceinline__ int bf_byte(int c, int t) {
    int p = ((c >> 2) & 3) | ((c & 3) << 2);   // bit-pair swap of c&15
    int s = (p ^ (c >> 4)) & 15;
    return c * 256 + ((t * 2) ^ (s << 4));
}

// fp32 -> bf16 (RNE), bit pattern as ushort
__device__ __forceinline__ unsigned short f2bf(float x) {
    unsigned u = __float_as_uint(x);
    unsigned r = (u + 0x7fffu + ((u >> 16) & 1u)) >> 16;
    return (unsigned short)r;
}

// ---------------- tiny zero kernel (graph-safe G clear) ----------------
__global__ void zero_kernel(float4* __restrict__ p, int n4) {
    int i = blockIdx.x * blockDim.x + threadIdx.x;
    if (i < n4) p[i] = make_float4(0.f, 0.f, 0.f, 0.f);
}

// ---- async DMA: chunk (128 rows x 400B, CONTIGUOUS in A) -> linear LDS raw ----
// 13 uniform global_load_lds(16B) per thread (clamped -> vmcnt uniform per wave).
// Zero register data path -> nothing to spill, nothing alive across barriers.
__device__ __forceinline__ void stage_issue(const float* __restrict__ A, long c0,
                                            char* raw, int tid, long dtot) {
    const long gword0 = c0 * (DK * NCLI);
    const long gmax = dtot * NCLI - 4;       // last safe float4 word start
    const int wbyte = (tid & ~63) << 4;      // wave-uniform byte base
#pragma unroll
    for (int i = 0; i < 13; ++i) {
        int f = i * 256 + tid;
        if (f > 3199) f = 3199;              // pad issues re-load last float4
        long gw = gword0 + (long)f * 4;
        if (gw > gmax) gw = gmax;
        __builtin_amdgcn_global_load_lds(
            (const __attribute__((address_space(1))) unsigned*)(A + gw),
            (__attribute__((address_space(3))) unsigned*)(raw + i * 4096 + wbyte),
            16, 0, 0);
    }
}

// ---- LDS->LDS transpose + fp32->bf16 convert (raw linear -> bf swizzled) ----
// 800 units (4-row x 4-col each); s<3 full, s=3 only tid<32.
__device__ __forceinline__ void transpose_convert(const char* raw, char* bf,
                                                  int tid, long d0, long dtot) {
#pragma unroll
    for (int s = 0; s < 4; ++s) {
        if (s < 3 || tid < 32) {
            const int u = tid + s * 256;
            const int rg = u / 25;           // 4-row group 0..31
            const int cg = u - rg * 25;      // 4-col group 0..24
            float4 v[4];
#pragma unroll
            for (int r = 0; r < 4; ++r) {
                v[r] = *(const float4*)(raw + (((rg * 4 + r) * 25 + cg) << 4));
                if (d0 + rg * 4 + r >= dtot) v[r] = make_float4(0.f, 0.f, 0.f, 0.f);
            }
#pragma unroll
            for (int j = 0; j < 4; ++j) {
                const int c = cg * 4 + j;
                ushort4 p;
                p.x = f2bf(((const float*)&v[0])[j]);
                p.y = f2bf(((const float*)&v[1])[j]);
                p.z = f2bf(((const float*)&v[2])[j]);
                p.w = f2bf(((const float*)&v[3])[j]);
                *(ushort4*)(bf + bf_byte(c, rg * 4)) = p;   // 8B, 8B-aligned
            }
        }
    }
}

// Wave W owns 16x16 output tiles: row a=W, b=W..6 (7-W tiles) and, for W>0,
// row a=7-W, b=7-W..6 (W tiles). Exactly 7 tiles per wave, A-frags {W, 7-W}.
template <int W>
__device__ __forceinline__ void compute_chunk(const char* bf, f32x4 acc[7]) {
    const int lane = threadIdx.x & 63;
    const int lrow = lane & 15;        // row/col within tile
    const int kgrp = lane >> 4;        // k-group 0..3 (8 bf16 each)
    constexpr int NB = 7 - W;          // b = W..6
#pragma unroll
    for (int kk = 0; kk < DK; kk += 32) {
        const int kb = kk + kgrp * 8;
        bf16x8 bfr[NB];
#pragma unroll
        for (int j = 0; j < NB; ++j)
            bfr[j] = *(const bf16x8*)(bf + bf_byte((W + j) * 16 + lrow, kb));
        bf16x8 a0 = *(const bf16x8*)(bf + bf_byte(W * 16 + lrow, kb));
#pragma unroll
        for (int j = 0; j < NB; ++j)
            acc[j] = __builtin_amdgcn_mfma_f32_16x16x32_bf16(a0, bfr[j], acc[j], 0, 0, 0);
        if constexpr (W > 0) {
            bf16x8 a1 = *(const bf16x8*)(bf + bf_byte((7 - W) * 16 + lrow, kb));
#pragma unroll
            for (int j = 0; j < W; ++j)
                acc[NB + j] = __builtin_amdgcn_mfma_f32_16x16x32_bf16(
                    a1, bfr[NB - W + j], acc[NB + j], 0, 0, 0);
        }
    }
}

template <int W>
__device__ __forceinline__ void store_acc(float* __restrict__ G, const f32x4 acc[7]) {
    const int lane = threadIdx.x & 63;
    const int cn = lane & 15;                 // output col within tile
    const int r0 = (lane >> 4) * 4;           // output row base within tile
#pragma unroll
    for (int j = 0; j < 7 - W; ++j) {         // tiles (W, W+j)
#pragma unroll
        for (int r = 0; r < 4; ++r) {
            int i = W * 16 + r0 + r;
            int k = (W + j) * 16 + cn;
            if (i < NCLI && k < NCLI) atomicAdd(&G[i * NCLI + k], acc[j][r]);
        }
    }
    if constexpr (W > 0) {
#pragma unroll
        for (int j = 0; j < W; ++j) {         // tiles (7-W, 7-W+j)
#pragma unroll
            for (int r = 0; r < 4; ++r) {
                int i = (7 - W) * 16 + r0 + r;
                int k = (7 - W + j) * 16 + cn;
                if (i < NCLI && k < NCLI) atomicAdd(&G[i * NCLI + k], acc[7 - W + j][r]);
            }
        }
    }
}

// ---------------- MFMA Gram, async-DMA pipelined, DK=128 ----------------
// r10-r12 model: per-CU gram time = chunks x (BW_time + F), F ~= 1us fixed
// SERIAL cost per chunk (depth- and occupancy-independent). Lever: fewer,
// bigger chunks. DK=128 -> 30.5 chunks/CU; predicted gram ~90-100us.
// LDS 132KB -> 1 block/CU (r11 vs r12: blocks/CU barely moves F).
__global__ __launch_bounds__(256, 1) void gram_mfma(const float* __restrict__ A,
                                                    float* __restrict__ G,
                                                    long dtot, int nchunks) {
    __shared__ char lds[2 * RAWB + BFB];   // 135168 B
    char* bf = lds + 2 * RAWB;
    const int tid = threadIdx.x;
    const int wid = tid >> 6;

    // zero bf pad-client rows 100..111 once (whole rows zero, swizzle-internal)
    for (int u = tid; u < (CPAD - NCLI) * 64; u += 256)
        ((unsigned*)(bf + NCLI * 256))[u] = 0u;
    __syncthreads();

    f32x4 acc[7];
#pragma unroll
    for (int q = 0; q < 7; ++q) acc[q] = (f32x4)(0.0f);

    int nb = 0;
    if ((int)blockIdx.x < nchunks)
        nb = (nchunks - 1 - (int)blockIdx.x) / (int)gridDim.x + 1;

    if (nb > 0)
        stage_issue(A, (long)blockIdx.x, lds, tid, dtot);   // prologue -> raw0

    for (int e = 0; e < nb; ++e) {
        char* raw_cur = lds + (e & 1) * RAWB;
        if (e + 1 < nb) {
            stage_issue(A, (long)blockIdx.x + (long)(e + 1) * gridDim.x,
                        lds + ((e + 1) & 1) * RAWB, tid, dtot);
            asm volatile("s_waitcnt vmcnt(13)" ::: "memory");  // drain chunk e only
        } else {
            asm volatile("s_waitcnt vmcnt(0)" ::: "memory");
        }
        __builtin_amdgcn_s_barrier();
        asm volatile("" ::: "memory");

        transpose_convert(raw_cur, bf, tid,
                          ((long)blockIdx.x + (long)e * gridDim.x) * DK, dtot);

        asm volatile("s_waitcnt lgkmcnt(0)" ::: "memory");
        __builtin_amdgcn_s_barrier();
        asm volatile("" ::: "memory");

        if (wid == 0)      compute_chunk<0>(bf, acc);
        else if (wid == 1) compute_chunk<1>(bf, acc);
        else if (wid == 2) compute_chunk<2>(bf, acc);
        else               compute_chunk<3>(bf, acc);
    }

    if (wid == 0)      store_acc<0>(G, acc);
    else if (wid == 1) store_acc<1>(G, acc);
    else if (wid == 2) store_acc<2>(G, acc);
    else               store_acc<3>(G, acc);
}

// ---------------- Weights kernel: full FoolsGold weight computation, single block ----------------
__global__ __launch_bounds__(128) void weights_kernel(const float* __restrict__ G,
                                                      float* __restrict__ w) {
    __shared__ float cs[NCLI][NCLI + 1];
    __shared__ float nrm[NCLI], maxcs[NCLI], wv[NCLI];
    __shared__ float red[2];
    const int t = threadIdx.x;

    if (t < NCLI) {
        float g = G[t * NCLI + t];
        nrm[t] = fmaxf(sqrtf(g), 1e-12f);
    }
    __syncthreads();

    for (int idx = t; idx < NCLI * NCLI; idx += 128) {
        int i = idx / NCLI;
        int j = idx - i * NCLI;
        int a = i < j ? i : j;
        int b = i < j ? j : i;
        float c = G[a * NCLI + b] / (nrm[i] * nrm[j]);
        if (i == j) c -= 1.0f;
        cs[i][j] = c;
    }
    __syncthreads();

    if (t < NCLI) {
        float m = -1e30f;
        for (int j = 0; j < NCLI; ++j) m = fmaxf(m, cs[t][j]);
        maxcs[t] = m;
    }
    __syncthreads();

    if (t < NCLI) {
        float mi = maxcs[t];
        float m = -1e30f;
        for (int j = 0; j < NCLI; ++j) {
            float v = cs[t][j];
            float mj = maxcs[j];
            if (t != j && mi < mj) v *= mi / mj;  // pardoning
            m = fmaxf(m, v);
        }
        float x = 1.0f - m;
        x = fminf(fmaxf(x, 0.0f), 1.0f);
        wv[t] = x;
    }
    __syncthreads();

    if (t == 0) {
        float m = 0.0f;
        for (int i = 0; i < NCLI; ++i) m = fmaxf(m, wv[i]);
        red[0] = m;
    }
    __syncthreads();

    if (t < NCLI) {
        float x = wv[t] / red[0];
        if (x == 1.0f) x = 0.99f;
        float l = logf(x / (1.0f - x)) + 0.5f;
        float flag = isinf(l) ? 1.0f : 0.0f;   // torch: wv[isinf(wv)+wv > 1] = 1
        l = (flag + l > 1.0f) ? 1.0f : l;
        l = (l < 0.0f) ? 0.0f : l;
        wv[t] = l;
    }
    __syncthreads();

    if (t == 0) {
        float s = 0.0f;
        for (int i = 0; i < NCLI; ++i) s += wv[i];
        red[1] = s;
    }
    __syncthreads();

    if (t < NCLI) w[t] = wv[t] / red[1];
}

// ---------------- Output kernel: out[j] = dot(A[j][:], w), quarter-row ----------------
// 4 lanes per row (q = (lane&3) + 4k): wave touches 16 rows x 64B contiguous
// segments per instruction -> small L1 window, no thrash (r10: -40us).
// Tail-first block->row mapping preserves gram's L3 tail residency.
__global__ __launch_bounds__(256) void out_kernel(const float* __restrict__ A,
                                                  const float* __restrict__ w,
                                                  float* __restrict__ out, int d,
                                                  int nblocks) {
    __shared__ float4 w4s[NCLI / 4];
    if (threadIdx.x < NCLI / 4) w4s[threadIdx.x] = ((const float4*)w)[threadIdx.x];
    __syncthreads();

    const int lane = threadIdx.x & 63;
    const int wid = threadIdx.x >> 6;
    const int q0 = lane & 3;                  // quarter id 0..3
    const int rsub = lane >> 2;               // row-within-wave 0..15

    const long rb = (long)(nblocks - 1 - blockIdx.x) * 64;   // 64 rows/block, tail-first
    const long row = rb + wid * 16 + rsub;
    if (row >= d) return;

    const float4* r4 = (const float4*)(A + row * NCLI);
    float s = 0.0f;
#pragma unroll
    for (int k = 0; k < 6; ++k) {             // q = q0 + 4k  (0..23)
        float4 v = r4[q0 + 4 * k];
        float4 ww = w4s[q0 + 4 * k];
        s += v.x * ww.x + v.y * ww.y + v.z * ww.z + v.w * ww.w;
    }
    if (q0 == 0) {                            // tail q = 24
        float4 v = r4[24];
        float4 ww = w4s[24];
        s += v.x * ww.x + v.y * ww.y + v.z * ww.z + v.w * ww.w;
    }
    // reduce across the 4-lane quarter group
    s += __shfl_xor(s, 1, 64);
    s += __shfl_xor(s, 2, 64);
    if (q0 == 0) out[row] = s;
}

extern "C" void kernel_launch(void* const* d_in, const int* in_sizes, int n_in,
                              void* d_out, int out_size, void* d_ws, size_t ws_size,
                              hipStream_t stream) {
    const float* A = (const float*)d_in[0];
    float* out = (float*)d_out;
    const int d = in_sizes[0] / NCLI;

    float* G = (float*)d_ws;           // 100*100 f32 (upper triangle used)
    float* w = G + NCLI * NCLI;        // 100 f32 weights

    const int n4 = (NCLI * NCLI) / 4;  // 2500 float4
    zero_kernel<<<(n4 + 255) / 256, 256, 0, stream>>>((float4*)G, n4);

    const int nchunks = (d + DK - 1) / DK;
    const int gblocks = nchunks < GBLK ? nchunks : GBLK;
    gram_mfma<<<gblocks, 256, 0, stream>>>(A, G, (long)d, nchunks);

    weights_kernel<<<1, 128, 0, stream>>>(G, w);

    const int oblocks = (d + 63) / 64;  // 64 rows per block
    out_kernel<<<oblocks, 256, 0, stream>>>(A, w, out, d, oblocks);
}

// Round 14
// 199.126 us; speedup vs baseline: 1.1732x; 1.0409x over previous
//
#include <hip/hip_runtime.h>
#include <math.h>

#define NCLI 100
#define CPAD 112                  // clients padded to 7*16
#define DK   64                   // d-rows per chunk
#define RAWB 25600                // raw fp32 buffer: 25 pages x 1024 B (exact)
#define BFB  (CPAD * DK * 2)      // 14336 B bf16 transposed buffer
#define GBLK 512                  // 2 blocks/CU x 256 CU

typedef short bf16x8 __attribute__((ext_vector_type(8)));  // 8 bf16 (4 VGPRs)
typedef float f32x4  __attribute__((ext_vector_type(4)));

// bf16 buffer byte offset for (client c, k-offset t). Row stride 128B = 8 x 16B
// slots; slot = (c&7) ^ ((c>>3)&7)  (r9/r10-verified: fragment reads 2-way=free,
// staging writes spread).
__device__ __forceinline__ int bf_byte(int c, int t) {
    int s = (c & 7) ^ ((c >> 3) & 7);
    return c * 128 + ((t * 2) ^ (s << 4));
}

// fp32 -> bf16 (RNE), bit pattern as ushort
__device__ __forceinline__ unsigned short f2bf(float x) {
    unsigned u = __float_as_uint(x);
    unsigned r = (u + 0x7fffu + ((u >> 16) & 1u)) >> 16;
    return (unsigned short)r;
}

// ---------------- tiny zero kernel (graph-safe G clear) ----------------
__global__ void zero_kernel(float4* __restrict__ p, int n4) {
    int i = blockIdx.x * blockDim.x + threadIdx.x;
    if (i < n4) p[i] = make_float4(0.f, 0.f, 0.f, 0.f);
}

// ---- async DMA, per-wave pages: chunk (64 rows x 400B, contiguous) -> raw ----
// 25 pages x 1024 B. Wave w copies pages 6w..6w+5; wave 0 also page 24.
// Per-wave issue counts: wave0=7, waves1-3=6 (vmcnt waits match per wave).
// LDS dest = wave-uniform page base (HW adds lane*16); global src per-lane,
// clamped. Zero register data path -> nothing to spill.
__device__ __forceinline__ void stage_issue(const float* __restrict__ A, long c0,
                                            char* raw, int tid, long dtot) {
    const int lane = tid & 63;
    const int w = tid >> 6;
    const long gword0 = c0 * (DK * NCLI);    // 6400 floats per chunk
    const long gmax = dtot * NCLI - 4;       // last safe float4 word start
#pragma unroll
    for (int p = 0; p < 6; ++p) {
        const int page = w * 6 + p;
        long gw = gword0 + page * 256 + lane * 4;
        if (gw > gmax) gw = gmax;
        __builtin_amdgcn_global_load_lds(
            (const __attribute__((address_space(1))) unsigned*)(A + gw),
            (__attribute__((address_space(3))) unsigned*)(raw + page * 1024),
            16, 0, 0);
    }
    if (w == 0) {
        long gw = gword0 + 24 * 256 + lane * 4;
        if (gw > gmax) gw = gmax;
        __builtin_amdgcn_global_load_lds(
            (const __attribute__((address_space(1))) unsigned*)(A + gw),
            (__attribute__((address_space(3))) unsigned*)(raw + 24 * 1024),
            16, 0, 0);
    }
}

// ---- LDS->LDS transpose + fp32->bf16 convert (raw linear -> bf swizzled) ----
// 400 units (4-row x 4-col each): s=0 all 256 threads, s=1 only tid<144.
__device__ __forceinline__ void transpose_convert(const char* raw, char* bf,
                                                  int tid, long d0, long dtot) {
#pragma unroll
    for (int s = 0; s < 2; ++s) {
        if (s == 0 || tid < 144) {
            const int u = tid + s * 256;
            const int rg = u / 25;           // 4-row group 0..15
            const int cg = u - rg * 25;      // 4-col group 0..24
            float4 v[4];
#pragma unroll
            for (int r = 0; r < 4; ++r) {
                v[r] = *(const float4*)(raw + (((rg * 4 + r) * 25 + cg) << 4));
                if (d0 + rg * 4 + r >= dtot) v[r] = make_float4(0.f, 0.f, 0.f, 0.f);
            }
#pragma unroll
            for (int j = 0; j < 4; ++j) {
                const int c = cg * 4 + j;
                ushort4 p;
                p.x = f2bf(((const float*)&v[0])[j]);
                p.y = f2bf(((const float*)&v[1])[j]);
                p.z = f2bf(((const float*)&v[2])[j]);
                p.w = f2bf(((const float*)&v[3])[j]);
                *(ushort4*)(bf + bf_byte(c, rg * 4)) = p;   // 8B, 8B-aligned
            }
        }
    }
}

// Wave W owns 16x16 output tiles: row a=W, b=W..6 (7-W tiles) and, for W>0,
// row a=7-W, b=7-W..6 (W tiles). Exactly 7 tiles per wave, A-frags {W, 7-W}.
template <int W>
__device__ __forceinline__ void compute_chunk(const char* bf, f32x4 acc[7]) {
    const int lane = threadIdx.x & 63;
    const int lrow = lane & 15;        // row/col within tile
    const int kgrp = lane >> 4;        // k-group 0..3 (8 bf16 each)
    constexpr int NB = 7 - W;          // b = W..6
#pragma unroll
    for (int kk = 0; kk < DK; kk += 32) {
        const int kb = kk + kgrp * 8;
        bf16x8 bfr[NB];
#pragma unroll
        for (int j = 0; j < NB; ++j)
            bfr[j] = *(const bf16x8*)(bf + bf_byte((W + j) * 16 + lrow, kb));
        bf16x8 a0 = *(const bf16x8*)(bf + bf_byte(W * 16 + lrow, kb));
#pragma unroll
        for (int j = 0; j < NB; ++j)
            acc[j] = __builtin_amdgcn_mfma_f32_16x16x32_bf16(a0, bfr[j], acc[j], 0, 0, 0);
        if constexpr (W > 0) {
            bf16x8 a1 = *(const bf16x8*)(bf + bf_byte((7 - W) * 16 + lrow, kb));
#pragma unroll
            for (int j = 0; j < W; ++j)
                acc[NB + j] = __builtin_amdgcn_mfma_f32_16x16x32_bf16(
                    a1, bfr[NB - W + j], acc[NB + j], 0, 0, 0);
        }
    }
}

template <int W>
__device__ __forceinline__ void store_acc(float* __restrict__ G, const f32x4 acc[7]) {
    const int lane = threadIdx.x & 63;
    const int cn = lane & 15;                 // output col within tile
    const int r0 = (lane >> 4) * 4;           // output row base within tile
#pragma unroll
    for (int j = 0; j < 7 - W; ++j) {         // tiles (W, W+j)
#pragma unroll
        for (int r = 0; r < 4; ++r) {
            int i = W * 16 + r0 + r;
            int k = (W + j) * 16 + cn;
            if (i < NCLI && k < NCLI) atomicAdd(&G[i * NCLI + k], acc[j][r]);
        }
    }
    if constexpr (W > 0) {
#pragma unroll
        for (int j = 0; j < W; ++j) {         // tiles (7-W, 7-W+j)
#pragma unroll
            for (int r = 0; r < 4; ++r) {
                int i = (7 - W) * 16 + r0 + r;
                int k = (7 - W + j) * 16 + cn;
                if (i < NCLI && k < NCLI) atomicAdd(&G[i * NCLI + k], acc[7 - W + j][r]);
            }
        }
    }
}

// ---------------- MFMA Gram: DMA pipeline + MERGED transpose/compute phase ----------------
// r10 skeleton (DK=64, B=2, depth-1 counted vmcnt) with the serial chain halved:
// per iteration e, ONE work phase runs { compute chunk e-1 from bf[(e-1)&1]  ||
// transpose chunk e -> bf[e&1] } between the same barrier pair (disjoint LDS).
// Race audit (each pair barrier-separated):
//   DMA(e+1)->raw[(e+1)&1] vs transpose(e-1) reads: iter e-1 final barrier.
//   transpose(e)->bf[e&1]  vs compute(e-2) reads bf[e&1]: iter e-1 final barrier.
//   compute(e-1) reads     vs transpose(e-1) writes: that iter's lgkm(0)+barrier.
__global__ __launch_bounds__(256, 2) void gram_mfma(const float* __restrict__ A,
                                                    float* __restrict__ G,
                                                    long dtot, int nchunks) {
    __shared__ uint4 ldsq[(2 * RAWB + 2 * BFB) / 16];   // 79872 B -> 2 blocks/CU
    char* lds = (char*)ldsq;
    char* bf = lds + 2 * RAWB;
    const int tid = threadIdx.x;
    const int wid = tid >> 6;

    // zero pad-client rows 100..111 in BOTH bf buffers (whole rows zero)
    for (int u = tid; u < 2 * (CPAD - NCLI) * 32; u += 256) {
        int b = u / ((CPAD - NCLI) * 32);
        int o = u - b * ((CPAD - NCLI) * 32);
        ((unsigned*)(bf + b * BFB + NCLI * 128))[o] = 0u;
    }
    __syncthreads();

    f32x4 acc[7];
#pragma unroll
    for (int q = 0; q < 7; ++q) acc[q] = (f32x4)(0.0f);

    int nb = 0;
    if ((int)blockIdx.x < nchunks)
        nb = (nchunks - 1 - (int)blockIdx.x) / (int)gridDim.x + 1;

    if (nb > 0)
        stage_issue(A, (long)blockIdx.x, lds, tid, dtot);   // prologue -> raw0

    for (int e = 0; e < nb; ++e) {
        if (e + 1 < nb) {
            stage_issue(A, (long)blockIdx.x + (long)(e + 1) * gridDim.x,
                        lds + ((e + 1) & 1) * RAWB, tid, dtot);
            // drain chunk e only; chunk e+1 (7/6 issues per wave) stays in flight
            if (wid == 0) asm volatile("s_waitcnt vmcnt(7)" ::: "memory");
            else          asm volatile("s_waitcnt vmcnt(6)" ::: "memory");
        } else {
            asm volatile("s_waitcnt vmcnt(0)" ::: "memory");
        }
        __builtin_amdgcn_s_barrier();
        asm volatile("" ::: "memory");

        // merged phase: compute previous chunk || transpose current chunk
        if (e > 0) {
            const char* bfp = bf + ((e - 1) & 1) * BFB;
            if (wid == 0)      compute_chunk<0>(bfp, acc);
            else if (wid == 1) compute_chunk<1>(bfp, acc);
            else if (wid == 2) compute_chunk<2>(bfp, acc);
            else               compute_chunk<3>(bfp, acc);
        }
        transpose_convert(lds + (e & 1) * RAWB, bf + (e & 1) * BFB, tid,
                          ((long)blockIdx.x + (long)e * gridDim.x) * DK, dtot);

        asm volatile("s_waitcnt lgkmcnt(0)" ::: "memory");
        __builtin_amdgcn_s_barrier();
        asm volatile("" ::: "memory");
    }

    // epilogue: compute the last chunk
    if (nb > 0) {
        const char* bfp = bf + ((nb - 1) & 1) * BFB;
        if (wid == 0)      compute_chunk<0>(bfp, acc);
        else if (wid == 1) compute_chunk<1>(bfp, acc);
        else if (wid == 2) compute_chunk<2>(bfp, acc);
        else               compute_chunk<3>(bfp, acc);
    }

    if (wid == 0)      store_acc<0>(G, acc);
    else if (wid == 1) store_acc<1>(G, acc);
    else if (wid == 2) store_acc<2>(G, acc);
    else               store_acc<3>(G, acc);
}

// ---------------- Weights kernel: full FoolsGold weight computation, single block ----------------
__global__ __launch_bounds__(128) void weights_kernel(const float* __restrict__ G,
                                                      float* __restrict__ w) {
    __shared__ float cs[NCLI][NCLI + 1];
    __shared__ float nrm[NCLI], maxcs[NCLI], wv[NCLI];
    __shared__ float red[2];
    const int t = threadIdx.x;

    if (t < NCLI) {
        float g = G[t * NCLI + t];
        nrm[t] = fmaxf(sqrtf(g), 1e-12f);
    }
    __syncthreads();

    for (int idx = t; idx < NCLI * NCLI; idx += 128) {
        int i = idx / NCLI;
        int j = idx - i * NCLI;
        int a = i < j ? i : j;
        int b = i < j ? j : i;
        float c = G[a * NCLI + b] / (nrm[i] * nrm[j]);
        if (i == j) c -= 1.0f;
        cs[i][j] = c;
    }
    __syncthreads();

    if (t < NCLI) {
        float m = -1e30f;
        for (int j = 0; j < NCLI; ++j) m = fmaxf(m, cs[t][j]);
        maxcs[t] = m;
    }
    __syncthreads();

    if (t < NCLI) {
        float mi = maxcs[t];
        float m = -1e30f;
        for (int j = 0; j < NCLI; ++j) {
            float v = cs[t][j];
            float mj = maxcs[j];
            if (t != j && mi < mj) v *= mi / mj;  // pardoning
            m = fmaxf(m, v);
        }
        float x = 1.0f - m;
        x = fminf(fmaxf(x, 0.0f), 1.0f);
        wv[t] = x;
    }
    __syncthreads();

    if (t == 0) {
        float m = 0.0f;
        for (int i = 0; i < NCLI; ++i) m = fmaxf(m, wv[i]);
        red[0] = m;
    }
    __syncthreads();

    if (t < NCLI) {
        float x = wv[t] / red[0];
        if (x == 1.0f) x = 0.99f;
        float l = logf(x / (1.0f - x)) + 0.5f;
        float flag = isinf(l) ? 1.0f : 0.0f;   // torch: wv[isinf(wv)+wv > 1] = 1
        l = (flag + l > 1.0f) ? 1.0f : l;
        l = (l < 0.0f) ? 0.0f : l;
        wv[t] = l;
    }
    __syncthreads();

    if (t == 0) {
        float s = 0.0f;
        for (int i = 0; i < NCLI; ++i) s += wv[i];
        red[1] = s;
    }
    __syncthreads();

    if (t < NCLI) w[t] = wv[t] / red[1];
}

// ---------------- Output kernel: out[j] = dot(A[j][:], w), quarter-row ----------------
// 4 lanes per row (q = (lane&3) + 4k): wave touches 16 rows x 64B contiguous
// segments per instruction -> small L1 window, no thrash (r10: -40us).
// Tail-first block->row mapping preserves gram's L3 tail residency.
__global__ __launch_bounds__(256) void out_kernel(const float* __restrict__ A,
                                                  const float* __restrict__ w,
                                                  float* __restrict__ out, int d,
                                                  int nblocks) {
    __shared__ float4 w4s[NCLI / 4];
    if (threadIdx.x < NCLI / 4) w4s[threadIdx.x] = ((const float4*)w)[threadIdx.x];
    __syncthreads();

    const int lane = threadIdx.x & 63;
    const int wid = threadIdx.x >> 6;
    const int q0 = lane & 3;                  // quarter id 0..3
    const int rsub = lane >> 2;               // row-within-wave 0..15

    const long rb = (long)(nblocks - 1 - blockIdx.x) * 64;   // 64 rows/block, tail-first
    const long row = rb + wid * 16 + rsub;
    if (row >= d) return;

    const float4* r4 = (const float4*)(A + row * NCLI);
    float s = 0.0f;
#pragma unroll
    for (int k = 0; k < 6; ++k) {             // q = q0 + 4k  (0..23)
        float4 v = r4[q0 + 4 * k];
        float4 ww = w4s[q0 + 4 * k];
        s += v.x * ww.x + v.y * ww.y + v.z * ww.z + v.w * ww.w;
    }
    if (q0 == 0) {                            // tail q = 24
        float4 v = r4[24];
        float4 ww = w4s[24];
        s += v.x * ww.x + v.y * ww.y + v.z * ww.z + v.w * ww.w;
    }
    // reduce across the 4-lane quarter group
    s += __shfl_xor(s, 1, 64);
    s += __shfl_xor(s, 2, 64);
    if (q0 == 0) out[row] = s;
}

extern "C" void kernel_launch(void* const* d_in, const int* in_sizes, int n_in,
                              void* d_out, int out_size, void* d_ws, size_t ws_size,
                              hipStream_t stream) {
    const float* A = (const float*)d_in[0];
    float* out = (float*)d_out;
    const int d = in_sizes[0] / NCLI;

    float* G = (float*)d_ws;           // 100*100 f32 (upper triangle used)
    float* w = G + NCLI * NCLI;        // 100 f32 weights

    const int n4 = (NCLI * NCLI) / 4;  // 2500 float4
    zero_kernel<<<(n4 + 255) / 256, 256, 0, stream>>>((float4*)G, n4);

    const int nchunks = (d + DK - 1) / DK;
    const int gblocks = nchunks < GBLK ? nchunks : GBLK;
    gram_mfma<<<gblocks, 256, 0, stream>>>(A, G, (long)d, nchunks);

    weights_kernel<<<1, 128, 0, stream>>>(G, w);

    const int oblocks = (d + 63) / 64;  // 64 rows per block
    out_kernel<<<oblocks, 256, 0, stream>>>(A, w, out, d, oblocks);
}